// Round 11
// baseline (469.994 us; speedup 1.0000x reference)
//
#include <hip/hip_runtime.h>

typedef short s8v __attribute__((ext_vector_type(8)));
typedef float f4v __attribute__((ext_vector_type(4)));

__device__ __forceinline__ unsigned short f2bf(float x) {
  union { float f; unsigned u; } v; v.f = x;
  unsigned r = v.u + 0x7fffu + ((v.u >> 16) & 1u);
  return (unsigned short)(r >> 16);
}
// RNE pack of two f32 -> bf16x2 in one VALU op (gfx950 v_cvt_pk_bf16_f32).
__device__ __forceinline__ unsigned pack_bf16x2(float lo, float hi) {
  unsigned r;
  asm("v_cvt_pk_bf16_f32 %0, %1, %2" : "=v"(r) : "v"(lo), "v"(hi));
  return r;
}
__device__ __forceinline__ s8v as_s8(int4 v) { union { int4 i; s8v s; } u; u.i = v; return u.s; }
__device__ __forceinline__ f4v as_f4(int4 v) { union { int4 i; f4v f; } u; u.i = v; return u.f; }
__device__ __forceinline__ int4 as_i4(f4v v) { union { f4v f; int4 i; } u; u.f = v; return u.i; }

// Workgroup barrier WITHOUT the vmcnt(0) drain __syncthreads() inserts.
__device__ __forceinline__ void bar_lgkm() {
  asm volatile("s_waitcnt lgkmcnt(0)" ::: "memory");
  __builtin_amdgcn_s_barrier();
  asm volatile("" ::: "memory");
}

// ---------------- prep: bf16 casts WITH fused row norms + weight reorg ----------------
__global__ __launch_bounds__(256) void prep_kernel(
    const float* __restrict__ q, const float* __restrict__ k,
    const float* __restrict__ w1, const float* __restrict__ w2, const float* __restrict__ w3,
    unsigned short* __restrict__ Qb, unsigned short* __restrict__ Kb,
    unsigned short* __restrict__ W1, unsigned short* __restrict__ W2,
    unsigned short* __restrict__ W3, float* __restrict__ nq, float* __restrict__ nk,
    float* __restrict__ accum) {
  __shared__ float part[4];
  int idx = blockIdx.x * 256 + threadIdx.x;
  const int NQ4 = (2048 * 512) / 4;
  if (idx < 2 * NQ4) {
    const bool isK = (idx >= NQ4);
    int ci = isK ? (idx - NQ4) : idx;
    float4 v = isK ? ((const float4*)k)[ci] : ((const float4*)q)[ci];
    uint2 pk = make_uint2(pack_bf16x2(v.x, v.y), pack_bf16x2(v.z, v.w));
    if (isK) ((uint2*)Kb)[ci] = pk; else ((uint2*)Qb)[ci] = pk;
    // fused row norm: row = ci >> 7 (128 threads/row)
    float s = v.x * v.x + v.y * v.y + v.z * v.z + v.w * v.w;
    for (int off = 32; off; off >>= 1) s += __shfl_xor(s, off);
    int wid = threadIdx.x >> 6;
    if ((threadIdx.x & 63) == 0) part[wid] = s;
    __syncthreads();
    if (threadIdx.x == 0) {
      int row = ci >> 7;
      float t = part[0] + part[1];
      if (isK) nk[row] = t; else nq[row] = t;
    }
    if (threadIdx.x == 128) {
      int row = ci >> 7;
      float t = part[2] + part[3];
      if (isK) nk[row] = t; else nq[row] = t;
    }
    return;
  }
  idx -= 2 * NQ4;
  if (idx < 3072) {                      // W1p [3 j][32 m][32 k]
    int j = idx >> 10, m = (idx >> 5) & 31, kk = idx & 31;
    int half = kk >> 4, kl = kk & 15, dy = 2 * j + half;
    float v = 0.f;
    if (m < 30 && kl < 10 && dy < 5) v = w1[m * 50 + (kl & 1) * 25 + dy * 5 + (kl >> 1)];
    W1[idx] = f2bf(v); return;
  }
  idx -= 3072;
  if (idx < 25600) {                     // W2 [5 dy][32 m][160 kk], kk = dx*32 + c
    int dy = idx / 5120, r = idx - dy * 5120, m = r / 160, kk = r - m * 160;
    int c = kk & 31, dx = kk >> 5;
    float v = 0.f;
    if (m < 30 && c < 30) v = w2[m * 750 + c * 25 + dy * 5 + dx];
    W2[idx] = f2bf(v); return;
  }
  idx -= 25600;
  if (idx < 288) {                       // W3 [9 dd=dy*3+dx][32 c]
    int dd = idx >> 5, c = idx & 31;
    float v = (c < 30) ? w3[c * 9 + dd] : 0.f;
    W3[idx] = f2bf(v); return;
  }
  idx -= 288;
  if (idx == 0) *accum = 0.f;
}

// ---------------- D = cdist GEMM ----------------
__global__ __launch_bounds__(256) void dgemm_kernel(
    const unsigned short* __restrict__ Qb, const unsigned short* __restrict__ Kb,
    const float* __restrict__ nq, const float* __restrict__ nk,
    const float* __restrict__ lq, const float* __restrict__ lk,
    float* __restrict__ Dout, unsigned* __restrict__ DPo) {
  __shared__ int4 sm[2 * 128 * 9];
  const int t = threadIdx.x;
  const int bm = blockIdx.x, bn = blockIdx.y;
  const int wv = t >> 6, l = t & 63;
  const int m0 = (wv & 1) * 64, n0 = (wv >> 1) * 64;
  const int l15 = l & 15, q4 = l >> 4;
  f4v acc[4][4] = {};
  const int4* Qg = (const int4*)Qb;
  const int4* Kg = (const int4*)Kb;
  for (int kt = 0; kt < 8; ++kt) {
    bar_lgkm();
#pragma unroll
    for (int i = 0; i < 4; ++i) {
      int c = t + i * 256;
      int row = c >> 3, kq = c & 7;
      sm[row * 9 + kq]        = Qg[(bm * 128 + row) * 64 + kt * 8 + kq];
      sm[1152 + row * 9 + kq] = Kg[(bn * 128 + row) * 64 + kt * 8 + kq];
    }
    bar_lgkm();
#pragma unroll
    for (int s = 0; s < 2; ++s) {
      s8v af[4], bfr[4];
#pragma unroll
      for (int mt = 0; mt < 4; ++mt)
        af[mt] = as_s8(sm[(m0 + mt * 16 + l15) * 9 + s * 4 + q4]);
#pragma unroll
      for (int nt = 0; nt < 4; ++nt)
        bfr[nt] = as_s8(sm[1152 + (n0 + nt * 16 + l15) * 9 + s * 4 + q4]);
#pragma unroll
      for (int mt = 0; mt < 4; ++mt)
#pragma unroll
        for (int nt = 0; nt < 4; ++nt)
          acc[mt][nt] = __builtin_amdgcn_mfma_f32_16x16x32_bf16(af[mt], bfr[nt], acc[mt][nt], 0, 0, 0);
    }
  }
  float nkv[4], lkv[4];
#pragma unroll
  for (int nt = 0; nt < 4; ++nt) {
    int gc = bn * 128 + n0 + nt * 16 + l15;
    nkv[nt] = nk[gc]; lkv[nt] = lk[gc];
  }
#pragma unroll
  for (int mt = 0; mt < 4; ++mt)
#pragma unroll
    for (int reg = 0; reg < 4; ++reg) {
      int gr = bm * 128 + m0 + mt * 16 + q4 * 4 + reg;
      float nqv = nq[gr], lqv = lq[gr];
#pragma unroll
      for (int nt = 0; nt < 4; ++nt) {
        int gc = bn * 128 + n0 + nt * 16 + l15;
        float d2 = nqv + nkv[nt] - 2.f * acc[mt][nt][reg];
        float Dv = sqrtf(fmaxf(d2, 0.f));
        Dout[gr * 2048 + gc] = Dv;
        float Pv = fabsf(lqv - lkv[nt]);
        DPo[gr * 2048 + gc] = pack_bf16x2(Dv, Pv);
      }
    }
}

// conv2 substep with STATIC phase P: accumulate act1 row RCV into fixed ring
// slots (slot(out-row o) = (o - rc0 + 2) mod 5, substep-invariant), emit slot P
// (= out row RCV-2), zero it. Replaces the data-shifting ring (R10) — removes
// 64 v_mov/interval on the conv2 waves. d descends so the emitted slot gets its
// final MFMA first (R4's verified pipe-drain ordering). All indices literal.
#define C2_SUB(P, RCV)                                                           \
  {                                                                              \
    const int rc_ = (RCV);                                                       \
    const int s4_ = rc_ & 3;                                                     \
    const int pa0_ = tp * 16 + l15;                                              \
    const int pb0_ = pa0_ + 16;                                                  \
    s8v fa_ = as_s8(a1s[(s4_ * 80 + pa0_) * 4 + (q4 ^ ((pa0_ >> 1) & 3))]);      \
    s8v fb_ = as_s8(a1s[(s4_ * 80 + pb0_) * 4 + (q4 ^ ((pb0_ >> 1) & 3))]);      \
    __builtin_amdgcn_s_setprio(1);                                               \
    _Pragma("unroll")                                                            \
    for (int s = 0; s < 5; ++s) {                                                \
      s8v na_ = fa_, nb_ = fb_;                                                  \
      if (s < 4) {                                                               \
        int qa_ = tp * 16 + l15 + s + 1;                                         \
        int qb_ = qa_ + 16;                                                      \
        na_ = as_s8(a1s[(s4_ * 80 + qa_) * 4 + (q4 ^ ((qa_ >> 1) & 3))]);        \
        nb_ = as_s8(a1s[(s4_ * 80 + qb_) * 4 + (q4 ^ ((qb_ >> 1) & 3))]);        \
      }                                                                          \
      _Pragma("unroll")                                                          \
      for (int d = 4; d >= 0; --d)                                               \
        ringA[((P) + 4 - d) % 5] = as_i4(__builtin_amdgcn_mfma_f32_16x16x32_bf16( \
            as_s8(uni[d * 5 + s]), fa_, as_f4(ringA[((P) + 4 - d) % 5]), 0, 0, 0)); \
      _Pragma("unroll")                                                          \
      for (int d = 4; d >= 0; --d)                                               \
        ringB[((P) + 4 - d) % 5] = as_i4(__builtin_amdgcn_mfma_f32_16x16x32_bf16( \
            as_s8(uni[d * 5 + s]), fb_, as_f4(ringB[((P) + 4 - d) % 5]), 0, 0, 0)); \
      fa_ = na_; fb_ = nb_;                                                      \
    }                                                                            \
    __builtin_amdgcn_s_setprio(0);                                               \
    const int r2c_ = rc_ - 2;                                                    \
    const bool vrow_ = (r2c_ >= y0 - 1 && r2c_ <= y0 + 46);                      \
    const int slotrow_ = vrow_ ? (r2c_ & 3) : 4;                                 \
    const bool rowin_ = vrow_ && (r2c_ >= 0) && (r2c_ < 2048);                   \
    {                                                                            \
      int px2 = tp * 16 + l15;                                                   \
      int gx2 = x0 - 1 + px2;                                                    \
      bool ok = rowin_ && (gx2 >= 0) && (gx2 < 2048);                            \
      f4v a = as_f4(ringA[(P)]);                                                 \
      float v0 = ok ? fmaxf(a[0] + bias4[0], 0.f) : 0.f;                         \
      float v1 = ok ? fmaxf(a[1] + bias4[1], 0.f) : 0.f;                         \
      float v2 = ok ? fmaxf(a[2] + bias4[2], 0.f) : 0.f;                         \
      float v3 = ok ? fmaxf(a[3] + bias4[3], 0.f) : 0.f;                         \
      int slot = (mb * 2 + (q4 >> 1)) ^ ((px2 >> 1) & 3);                        \
      *(uint2*)((unsigned short*)a2s + (slotrow_ * 68 + px2) * 32 + slot * 8 + (q4 & 1) * 4) = \
          make_uint2(pack_bf16x2(v0, v1), pack_bf16x2(v2, v3));                  \
    }                                                                            \
    {                                                                            \
      int px2 = tp * 16 + 16 + l15;                                              \
      int gx2 = x0 - 1 + px2;                                                    \
      bool ok = rowin_ && (gx2 >= 0) && (gx2 < 2048);                            \
      f4v a = as_f4(ringB[(P)]);                                                 \
      float v0 = ok ? fmaxf(a[0] + bias4[0], 0.f) : 0.f;                         \
      float v1 = ok ? fmaxf(a[1] + bias4[1], 0.f) : 0.f;                         \
      float v2 = ok ? fmaxf(a[2] + bias4[2], 0.f) : 0.f;                         \
      float v3 = ok ? fmaxf(a[3] + bias4[3], 0.f) : 0.f;                         \
      int slot = (mb * 2 + (q4 >> 1)) ^ ((px2 >> 1) & 3);                        \
      *(uint2*)((unsigned short*)a2s + (slotrow_ * 68 + px2) * 32 + slot * 8 + (q4 & 1) * 4) = \
          make_uint2(pack_bf16x2(v0, v1), pack_bf16x2(v2, v3));                  \
    }                                                                            \
    ringA[(P)] = make_int4(0, 0, 0, 0);                                          \
    ringB[(P)] = make_int4(0, 0, 0, 0);                                          \
  }

// ---------------- fused conv, R10 structure + static-phase conv2 rings ----------------
__global__ __launch_bounds__(512, 2) void fused_conv(
    const unsigned* __restrict__ DPg, const float* __restrict__ Dmat,
    const unsigned short* __restrict__ W1g, const unsigned short* __restrict__ W2g,
    const unsigned short* __restrict__ W3g,
    const float* __restrict__ b1, const float* __restrict__ b2, const float* __restrict__ b3,
    float* __restrict__ Sout) {
  __shared__ int4 a1s[1600];       // [5][80][4]  slot 4 = scratch
  __shared__ int4 a2s[1360];       // [5][68][4]  slot 4 = scratch
  __shared__ unsigned dps[1700];   // [17][100]   row 16 = scratch
  const int t = threadIdx.x;
  const int wv = t >> 6, l = t & 63, l15 = l & 15, q4 = l >> 4;
  const int x0 = blockIdx.x * 62, y0 = blockIdx.y * 46;

  int4 uni[25];     // conv2: W2[dy][s] ; conv3: shift regs [tt][3]
  int4 uni2[5];     // conv1: W1p[j] ; conv3: W3[dx]
  int4 ringA[5], ringB[5];  // conv2 acc rings (static-phase slots)
  float bias4[4];
  const int cls = (wv < 4) ? 0 : (wv < 6 ? 1 : 2);
  const int mb = (cls == 0) ? (wv >> 1) : (wv & 1);
  const int tp = (wv & 1) * 2;          // conv2 tile-pair base (tiles tp, tp+1)
  const int T3 = (wv - 6) * 2;

  // staging pipeline registers (cls 2 only) — two rows in flight
  unsigned pvO0 = 0u, pvO1 = 0u;
  float d0Oa = 0.f, d1Oa = 0.f, d0Ob = 0.f, d1Ob = 0.f;
  const int spx = (wv == 6) ? l : (64 + l);
  const int sgx = x0 - 5 + spx;
  const bool scol = (spx < 96) && (sgx >= 0) && (sgx < 2048);
  const int sgxc = min(max(sgx, 0), 2047);

  if (cls == 0) {
    const int4* W2i = (const int4*)W2g;
#pragma unroll
    for (int d = 0; d < 5; ++d)
#pragma unroll
      for (int s = 0; s < 5; ++s)
        uni[d * 5 + s] = W2i[(d * 32 + mb * 16 + l15) * 20 + s * 4 + q4];
#pragma unroll
    for (int j = 0; j < 5; ++j) { ringA[j] = make_int4(0, 0, 0, 0); ringB[j] = make_int4(0, 0, 0, 0); }
#pragma unroll
    for (int i = 0; i < 4; ++i) {
      int ch = mb * 16 + q4 * 4 + i;
      bias4[i] = (ch < 30) ? b2[ch] : 0.f;
    }
  } else if (cls == 1) {
    const int4* W1i = (const int4*)W1g;
#pragma unroll
    for (int j = 0; j < 3; ++j) uni2[j] = W1i[(j * 32 + mb * 16 + l15) * 4 + q4];
#pragma unroll
    for (int i = 0; i < 4; ++i) {
      int ch = mb * 16 + q4 * 4 + i;
      bias4[i] = (ch < 30) ? b1[ch] : 0.f;
    }
  } else {
    const int4* W3i = (const int4*)W3g;
#pragma unroll
    for (int dx = 0; dx < 3; ++dx)
      uni2[dx] = (l15 < 3) ? W3i[(l15 * 3 + dx) * 4 + q4] : make_int4(0, 0, 0, 0);
#pragma unroll
    for (int j = 0; j < 6; ++j) uni[j] = make_int4(0, 0, 0, 0);
    bias4[0] = b3[0];
    // prologue: preload DP rows y0+1, y0+2 (written to ring at end of first interval)
    if (scol) {
      pvO0 = DPg[(y0 + 1) * 2048 + sgx];
      pvO1 = DPg[(y0 + 2) * 2048 + sgx];
    }
  }
  // prefill DP rows y0-5 .. y0 (576 items over 512 threads: two passes)
  {
    int row = y0 - 5 + t / 96, px = t % 96;
    int gx = x0 - 5 + px;
    unsigned v = 0u;
    if (row >= 0 && row < 2048 && gx >= 0 && gx < 2048) v = DPg[row * 2048 + gx];
    dps[(row & 15) * 100 + px] = v;
  }
  {
    int t2 = t + 512;
    if (t2 < 576) {
      int row = y0 - 5 + t2 / 96, px = t2 % 96;
      int gx = x0 - 5 + px;
      unsigned v = 0u;
      if (row >= 0 && row < 2048 && gx >= 0 && gx < 2048) v = DPg[row * 2048 + gx];
      dps[(row & 15) * 100 + px] = v;
    }
  }
  // zero act2 pad px 64..67 (all 5 slots: 80 int4)
  if (t >= 144 && t < 224) {
    int i = t - 144;
    int sl = i / 16, rem = i & 15;
    a2s[(sl * 68 + 64 + (rem >> 2)) * 4 + (rem & 3)] = make_int4(0, 0, 0, 0);
  }
  __syncthreads();

  int r = y0 - 3;
  int ph = 0;   // interval phase: substep phases (2u)%5, (2u+1)%5 — period 5
  for (int u = 0; u < 28; ++u) {
    if (cls == 0) {
      switch (ph) {
        case 0:  C2_SUB(0, r - 2) C2_SUB(1, r - 1) break;
        case 1:  C2_SUB(2, r - 2) C2_SUB(3, r - 1) break;
        case 2:  C2_SUB(4, r - 2) C2_SUB(0, r - 1) break;
        case 3:  C2_SUB(1, r - 2) C2_SUB(2, r - 1) break;
        default: C2_SUB(3, r - 2) C2_SUB(4, r - 1) break;
      }
    } else if (cls == 1) {
      // ---- conv1: produce act1 rows r and r+1, T1+1 lookahead ----
#pragma unroll
      for (int pr = 0; pr < 2; ++pr) {
        int p = r + pr;
        f4v a5[5];
        // prime T1=0 reads
        int4 c0, c1, c2;
        {
          int px = l15;
          int rl0 = p - 2, rl1 = p, rl2 = p + 2;
          int rs0 = (q4 < 2) ? rl0 : (rl0 + 1);
          int rs1 = (q4 < 2) ? rl1 : (rl1 + 1);
          c0 = *(const int4*)(dps + (rs0 & 15) * 100 + px + (q4 & 1) * 4);
          c1 = *(const int4*)(dps + (rs1 & 15) * 100 + px + (q4 & 1) * 4);
          c2 = *(const int4*)(dps + (rl2 & 15) * 100 + px + (q4 & 1) * 4);
        }
        __builtin_amdgcn_s_setprio(1);
#pragma unroll
        for (int T1 = 0; T1 < 5; ++T1) {
          int4 n0 = c0, n1 = c1, n2 = c2;
          if (T1 < 4) {  // issue next-tile reads BEFORE this tile's MFMAs
            int px = (T1 + 1) * 16 + l15;
            int rl0 = p - 2, rl1 = p, rl2 = p + 2;
            int rs0 = (q4 < 2) ? rl0 : (rl0 + 1);
            int rs1 = (q4 < 2) ? rl1 : (rl1 + 1);
            n0 = *(const int4*)(dps + (rs0 & 15) * 100 + px + (q4 & 1) * 4);
            n1 = *(const int4*)(dps + (rs1 & 15) * 100 + px + (q4 & 1) * 4);
            n2 = *(const int4*)(dps + (rl2 & 15) * 100 + px + (q4 & 1) * 4);
          }
          f4v acc = {0.f, 0.f, 0.f, 0.f};
          acc = __builtin_amdgcn_mfma_f32_16x16x32_bf16(as_s8(uni2[0]), as_s8(c0), acc, 0, 0, 0);
          acc = __builtin_amdgcn_mfma_f32_16x16x32_bf16(as_s8(uni2[1]), as_s8(c1), acc, 0, 0, 0);
          acc = __builtin_amdgcn_mfma_f32_16x16x32_bf16(as_s8(uni2[2]), as_s8(c2), acc, 0, 0, 0);
          a5[T1] = acc;
          c0 = n0; c1 = n1; c2 = n2;
        }
        __builtin_amdgcn_s_setprio(0);
        bool vrow = (p >= y0 - 3 && p <= y0 + 48);
        int slotrow = vrow ? (p & 3) : 4;
        bool rowok = vrow && (p >= 0 && p < 2048);
#pragma unroll
        for (int T1 = 0; T1 < 5; ++T1) {
          int px = T1 * 16 + l15;
          int gx = x0 - 3 + px;
          bool ok = rowok && gx >= 0 && gx < 2048;
          float v0 = ok ? fmaxf(a5[T1][0] + bias4[0], 0.f) : 0.f;
          float v1 = ok ? fmaxf(a5[T1][1] + bias4[1], 0.f) : 0.f;
          float v2 = ok ? fmaxf(a5[T1][2] + bias4[2], 0.f) : 0.f;
          float v3 = ok ? fmaxf(a5[T1][3] + bias4[3], 0.f) : 0.f;
          int slot = (mb * 2 + (q4 >> 1)) ^ ((px >> 1) & 3);
          *(uint2*)((unsigned short*)a1s + (slotrow * 80 + px) * 32 + slot * 8 + (q4 & 1) * 4) =
              make_uint2(pack_bf16x2(v0, v1), pack_bf16x2(v2, v3));
        }
      }
    } else {
      // ---- staging loads for DP rows r+6, r+7 (clamped, branchless) ----
      int rsN0 = r + 6, rsN1 = r + 7;
      unsigned tmp0 = DPg[min(rsN0, 2047) * 2048 + sgxc];
      unsigned tmp1 = DPg[min(rsN1, 2047) * 2048 + sgxc];
      unsigned pvN0 = (scol && rsN0 < 2048) ? tmp0 : 0u;
      unsigned pvN1 = (scol && rsN1 < 2048) ? tmp1 : 0u;
      // ---- residual loads for out rows r-5, r-4 (clamped, branchless) ----
      int gx0 = x0 + T3 * 16 + l15;
      int gx0c = min(gx0, 2047), gx1c = min(gx0 + 16, 2047);
      int yn0c = min(max(r - 5, 0), 2047), yn1c = min(max(r - 4, 0), 2047);
      float d0Na = Dmat[yn0c * 2048 + gx0c];
      float d1Na = Dmat[yn0c * 2048 + gx1c];
      float d0Nb = Dmat[yn1c * 2048 + gx0c];
      float d1Nb = Dmat[yn1c * 2048 + gx1c];
      // ---- hoist ALL conv3 LDS reads (both substeps) above the MFMA clusters ----
      s8v Bf[12];   // [sub*6 + tt*3 + dx]
#pragma unroll
      for (int sub = 0; sub < 2; ++sub) {
        int s4 = (r - 6 + sub) & 3;
#pragma unroll
        for (int tt = 0; tt < 2; ++tt)
#pragma unroll
          for (int dx = 0; dx < 3; ++dx) {
            int px2 = (T3 + tt) * 16 + l15 + dx;
            Bf[sub * 6 + tt * 3 + dx] =
                as_s8(a2s[(s4 * 68 + px2) * 4 + (q4 ^ ((px2 >> 1) & 3))]);
          }
      }
      // ---- conv3 substep A: consume act2 row r-6 (unconditional) ----
      float eA0, eA1, eA2, eA3, eA4, eA5;
      {
        __builtin_amdgcn_s_setprio(1);
#pragma unroll
        for (int tt = 0; tt < 2; ++tt) {
          f4v acc3 = {0.f, 0.f, 0.f, 0.f};
#pragma unroll
          for (int dx = 0; dx < 3; ++dx)
            acc3 = __builtin_amdgcn_mfma_f32_16x16x32_bf16(
                as_s8(uni2[dx]), Bf[tt * 3 + dx], acc3, 0, 0, 0);
          uni[tt * 3 + 2] = as_i4(acc3);
        }
        __builtin_amdgcn_s_setprio(0);
        eA0 = as_f4(uni[0])[0]; eA1 = as_f4(uni[1])[1]; eA2 = as_f4(uni[2])[2];
        eA3 = as_f4(uni[3])[0]; eA4 = as_f4(uni[4])[1]; eA5 = as_f4(uni[5])[2];
#pragma unroll
        for (int tt = 0; tt < 2; ++tt) {
          uni[tt * 3 + 0] = uni[tt * 3 + 1];
          uni[tt * 3 + 1] = uni[tt * 3 + 2];
        }
      }
      // ---- conv3 substep B: consume act2 row r-5 (unconditional) ----
      float eB0, eB1, eB2, eB3, eB4, eB5;
      {
        __builtin_amdgcn_s_setprio(1);
#pragma unroll
        for (int tt = 0; tt < 2; ++tt) {
          f4v acc3 = {0.f, 0.f, 0.f, 0.f};
#pragma unroll
          for (int dx = 0; dx < 3; ++dx)
            acc3 = __builtin_amdgcn_mfma_f32_16x16x32_bf16(
                as_s8(uni2[dx]), Bf[6 + tt * 3 + dx], acc3, 0, 0, 0);
          uni[tt * 3 + 2] = as_i4(acc3);
        }
        __builtin_amdgcn_s_setprio(0);
        eB0 = as_f4(uni[0])[0]; eB1 = as_f4(uni[1])[1]; eB2 = as_f4(uni[2])[2];
        eB3 = as_f4(uni[3])[0]; eB4 = as_f4(uni[4])[1]; eB5 = as_f4(uni[5])[2];
#pragma unroll
        for (int tt = 0; tt < 2; ++tt) {
          uni[tt * 3 + 0] = uni[tt * 3 + 1];
          uni[tt * 3 + 1] = uni[tt * 3 + 2];
        }
      }
      // ---- deferred emits: out rows r-7 (A), r-6 (B) — exec-masked stores ----
      {
        int y = r - 7;
        bool yok = (y >= y0 && y <= y0 + 45 && y < 2048);
        int gxa = x0 + T3 * 16 + l15;
        int gxb = gxa + 16;
        if (q4 == 0 && yok && gxa < 2048)
          Sout[y * 2048 + gxa] = eA0 + eA1 + eA2 + bias4[0] + d0Oa;
        if (q4 == 0 && yok && (T3 + 1) * 16 + l15 < 62 && gxb < 2048)
          Sout[y * 2048 + gxb] = eA3 + eA4 + eA5 + bias4[0] + d1Oa;
      }
      {
        int y = r - 6;
        bool yok = (y >= y0 && y <= y0 + 45 && y < 2048);
        int gxa = x0 + T3 * 16 + l15;
        int gxb = gxa + 16;
        if (q4 == 0 && yok && gxa < 2048)
          Sout[y * 2048 + gxa] = eB0 + eB1 + eB2 + bias4[0] + d0Ob;
        if (q4 == 0 && yok && (T3 + 1) * 16 + l15 < 62 && gxb < 2048)
          Sout[y * 2048 + gxb] = eB3 + eB4 + eB5 + bias4[0] + d1Ob;
      }
      // ---- write staging rows r+4, r+5 (scratch-redirected) ----
      {
        int rs0 = r + 4, rs1 = r + 5;
        int wr0 = (rs0 <= y0 + 50) ? (rs0 & 15) : 16;
        int wr1 = (rs1 <= y0 + 50) ? (rs1 & 15) : 16;
        if (spx < 96) {
          dps[wr0 * 100 + spx] = pvO0;
          dps[wr1 * 100 + spx] = pvO1;
        }
      }
      pvO0 = pvN0; pvO1 = pvN1;
      d0Oa = d0Na; d1Oa = d1Na; d0Ob = d0Nb; d1Ob = d1Nb;
    }
    bar_lgkm();
    r += 2;
    ph = (ph == 4) ? 0 : (ph + 1);
  }
}

// ---------------- row softmax (in-place, float4-vectorized) + dis accumulation ----------------
__global__ __launch_bounds__(256) void softmax_kernel(
    float* __restrict__ S, const float* __restrict__ Dmat, float* __restrict__ accum) {
  const int row = blockIdx.x, t = threadIdx.x;
  float* Srow = S + row * 2048;
  const float* Drow = Dmat + row * 2048;
  float4 s0 = ((const float4*)Srow)[2 * t];
  float4 s1 = ((const float4*)Srow)[2 * t + 1];
  float4 g0 = ((const float4*)Drow)[2 * t];
  float4 g1 = ((const float4*)Drow)[2 * t + 1];
  float sv[8] = {-s0.x, -s0.y, -s0.z, -s0.w, -s1.x, -s1.y, -s1.z, -s1.w};
  float dv[8] = {g0.x, g0.y, g0.z, g0.w, g1.x, g1.y, g1.z, g1.w};
  float mx = -1e30f;
#pragma unroll
  for (int i = 0; i < 8; ++i) mx = fmaxf(mx, sv[i]);
  __shared__ float red[4], redz[4], redw[4];
  for (int off = 32; off; off >>= 1) mx = fmaxf(mx, __shfl_xor(mx, off));
  const int wv = t >> 6, l = t & 63;
  if (l == 0) red[wv] = mx;
  __syncthreads();
  mx = fmaxf(fmaxf(red[0], red[1]), fmaxf(red[2], red[3]));
  float z = 0.f, w = 0.f, ev[8];
#pragma unroll
  for (int i = 0; i < 8; ++i) {
    ev[i] = __expf(sv[i] - mx);
    z += ev[i];
    w += ev[i] * dv[i];
  }
  for (int off = 32; off; off >>= 1) { z += __shfl_xor(z, off); w += __shfl_xor(w, off); }
  if (l == 0) { redz[wv] = z; redw[wv] = w; }
  __syncthreads();
  z = redz[0] + redz[1] + redz[2] + redz[3];
  w = redw[0] + redw[1] + redw[2] + redw[3];
  float inv = 1.f / z;
  float4 o0 = make_float4(ev[0] * inv, ev[1] * inv, ev[2] * inv, ev[3] * inv);
  float4 o1 = make_float4(ev[4] * inv, ev[5] * inv, ev[6] * inv, ev[7] * inv);
  ((float4*)Srow)[2 * t] = o0;
  ((float4*)Srow)[2 * t + 1] = o1;
  if (t == 0) atomicAdd(accum, w * inv);
}

__global__ void finalize_kernel(const float* __restrict__ accum, float* __restrict__ out) {
  if (threadIdx.x == 0) out[0] = accum[0] * (1.f / 2048.f);
}

// ---------------- host ----------------
extern "C" void kernel_launch(void* const* d_in, const int* in_sizes, int n_in,
                              void* d_out, int out_size, void* d_ws, size_t ws_size,
                              hipStream_t stream) {
  const float* seq_q = (const float*)d_in[0];
  const float* seq_k = (const float*)d_in[1];
  const float* len_q = (const float*)d_in[2];
  const float* len_k = (const float*)d_in[3];
  const float* w1 = (const float*)d_in[4];
  const float* b1 = (const float*)d_in[5];
  const float* w2 = (const float*)d_in[6];
  const float* b2 = (const float*)d_in[7];
  const float* w3 = (const float*)d_in[8];
  const float* b3 = (const float*)d_in[9];

  char* ws = (char*)d_ws;
  unsigned short* Qb  = (unsigned short*)(ws);                         // 2 MiB
  unsigned short* Kb  = (unsigned short*)(ws + ((size_t)2 << 20));     // 2 MiB
  float* nq           = (float*)(ws + ((size_t)4 << 20));              // 8 KiB
  float* nk           = (float*)(ws + ((size_t)4 << 20) + 16384);
  unsigned short* W1  = (unsigned short*)(ws + ((size_t)4 << 20) + 32768);   // 6 KiB (packed)
  unsigned short* W2  = (unsigned short*)(ws + ((size_t)4 << 20) + 65536);   // 50 KiB
  unsigned short* W3  = (unsigned short*)(ws + ((size_t)4 << 20) + 131072);  // 576 B
  float* accum        = (float*)(ws + ((size_t)4 << 20) + 163840);
  float* Dmat         = (float*)(ws + ((size_t)5 << 20));              // 16 MiB fp32
  unsigned* DPo       = (unsigned*)(ws + ((size_t)22 << 20));          // 16 MiB packed (D,P)
  float* out = (float*)d_out;

  // prep: casts+norms fused (2*NQ4, block-aligned) + weights + accum
  const int prep_total = 2 * ((2048 * 512) / 4) + 3072 + 25600 + 288 + 1;
  prep_kernel<<<(prep_total + 255) / 256, 256, 0, stream>>>(
      seq_q, seq_k, w1, w2, w3, Qb, Kb, W1, W2, W3, nq, nk, accum);
  dgemm_kernel<<<dim3(16, 16), 256, 0, stream>>>(Qb, Kb, nq, nk, len_q, len_k, Dmat, DPo);
  fused_conv<<<dim3(34, 45), 512, 0, stream>>>(
      DPo, Dmat, W1, W2, W3, b1, b2, b3, out);
  softmax_kernel<<<2048, 256, 0, stream>>>(out, Dmat, accum);
  finalize_kernel<<<1, 64, 0, stream>>>(accum, out + 4194304);
}

// Round 12
// 442.661 us; speedup vs baseline: 1.0617x; 1.0617x over previous
//
#include <hip/hip_runtime.h>

typedef short s8v __attribute__((ext_vector_type(8)));
typedef float f4v __attribute__((ext_vector_type(4)));

__device__ __forceinline__ unsigned short f2bf(float x) {
  union { float f; unsigned u; } v; v.f = x;
  unsigned r = v.u + 0x7fffu + ((v.u >> 16) & 1u);
  return (unsigned short)(r >> 16);
}
// RNE pack of two f32 -> bf16x2 in one VALU op (gfx950 v_cvt_pk_bf16_f32).
__device__ __forceinline__ unsigned pack_bf16x2(float lo, float hi) {
  unsigned r;
  asm("v_cvt_pk_bf16_f32 %0, %1, %2" : "=v"(r) : "v"(lo), "v"(hi));
  return r;
}
__device__ __forceinline__ s8v as_s8(int4 v) { union { int4 i; s8v s; } u; u.i = v; return u.s; }
__device__ __forceinline__ f4v as_f4(int4 v) { union { int4 i; f4v f; } u; u.i = v; return u.f; }
__device__ __forceinline__ int4 as_i4(f4v v) { union { f4v f; int4 i; } u; u.f = v; return u.i; }

// Workgroup barrier WITHOUT the vmcnt(0) drain __syncthreads() inserts.
__device__ __forceinline__ void bar_lgkm() {
  asm volatile("s_waitcnt lgkmcnt(0)" ::: "memory");
  __builtin_amdgcn_s_barrier();
  asm volatile("" ::: "memory");
}

// ---------------- prep: bf16 casts WITH fused row norms + weight reorg ----------------
__global__ __launch_bounds__(256) void prep_kernel(
    const float* __restrict__ q, const float* __restrict__ k,
    const float* __restrict__ w1, const float* __restrict__ w2, const float* __restrict__ w3,
    unsigned short* __restrict__ Qb, unsigned short* __restrict__ Kb,
    unsigned short* __restrict__ W1, unsigned short* __restrict__ W2,
    unsigned short* __restrict__ W3, float* __restrict__ nq, float* __restrict__ nk,
    float* __restrict__ accum) {
  __shared__ float part[4];
  int idx = blockIdx.x * 256 + threadIdx.x;
  const int NQ4 = (2048 * 512) / 4;
  if (idx < 2 * NQ4) {
    const bool isK = (idx >= NQ4);
    int ci = isK ? (idx - NQ4) : idx;
    float4 v = isK ? ((const float4*)k)[ci] : ((const float4*)q)[ci];
    uint2 pk = make_uint2(pack_bf16x2(v.x, v.y), pack_bf16x2(v.z, v.w));
    if (isK) ((uint2*)Kb)[ci] = pk; else ((uint2*)Qb)[ci] = pk;
    // fused row norm: row = ci >> 7 (128 threads/row)
    float s = v.x * v.x + v.y * v.y + v.z * v.z + v.w * v.w;
    for (int off = 32; off; off >>= 1) s += __shfl_xor(s, off);
    int wid = threadIdx.x >> 6;
    if ((threadIdx.x & 63) == 0) part[wid] = s;
    __syncthreads();
    if (threadIdx.x == 0) {
      int row = ci >> 7;
      float t = part[0] + part[1];
      if (isK) nk[row] = t; else nq[row] = t;
    }
    if (threadIdx.x == 128) {
      int row = ci >> 7;
      float t = part[2] + part[3];
      if (isK) nk[row] = t; else nq[row] = t;
    }
    return;
  }
  idx -= 2 * NQ4;
  if (idx < 3072) {                      // W1p [3 j][32 m][32 k]
    int j = idx >> 10, m = (idx >> 5) & 31, kk = idx & 31;
    int half = kk >> 4, kl = kk & 15, dy = 2 * j + half;
    float v = 0.f;
    if (m < 30 && kl < 10 && dy < 5) v = w1[m * 50 + (kl & 1) * 25 + dy * 5 + (kl >> 1)];
    W1[idx] = f2bf(v); return;
  }
  idx -= 3072;
  if (idx < 25600) {                     // W2 [5 dy][32 m][160 kk], kk = dx*32 + c
    int dy = idx / 5120, r = idx - dy * 5120, m = r / 160, kk = r - m * 160;
    int c = kk & 31, dx = kk >> 5;
    float v = 0.f;
    if (m < 30 && c < 30) v = w2[m * 750 + c * 25 + dy * 5 + dx];
    W2[idx] = f2bf(v); return;
  }
  idx -= 25600;
  if (idx < 288) {                       // W3 [9 dd=dy*3+dx][32 c]
    int dd = idx >> 5, c = idx & 31;
    float v = (c < 30) ? w3[c * 9 + dd] : 0.f;
    W3[idx] = f2bf(v); return;
  }
  idx -= 288;
  if (idx == 0) *accum = 0.f;
}

// ---------------- D = cdist GEMM ----------------
__global__ __launch_bounds__(256) void dgemm_kernel(
    const unsigned short* __restrict__ Qb, const unsigned short* __restrict__ Kb,
    const float* __restrict__ nq, const float* __restrict__ nk,
    const float* __restrict__ lq, const float* __restrict__ lk,
    float* __restrict__ Dout, unsigned* __restrict__ DPo) {
  __shared__ int4 sm[2 * 128 * 9];
  const int t = threadIdx.x;
  const int bm = blockIdx.x, bn = blockIdx.y;
  const int wv = t >> 6, l = t & 63;
  const int m0 = (wv & 1) * 64, n0 = (wv >> 1) * 64;
  const int l15 = l & 15, q4 = l >> 4;
  f4v acc[4][4] = {};
  const int4* Qg = (const int4*)Qb;
  const int4* Kg = (const int4*)Kb;
  for (int kt = 0; kt < 8; ++kt) {
    bar_lgkm();
#pragma unroll
    for (int i = 0; i < 4; ++i) {
      int c = t + i * 256;
      int row = c >> 3, kq = c & 7;
      sm[row * 9 + kq]        = Qg[(bm * 128 + row) * 64 + kt * 8 + kq];
      sm[1152 + row * 9 + kq] = Kg[(bn * 128 + row) * 64 + kt * 8 + kq];
    }
    bar_lgkm();
#pragma unroll
    for (int s = 0; s < 2; ++s) {
      s8v af[4], bfr[4];
#pragma unroll
      for (int mt = 0; mt < 4; ++mt)
        af[mt] = as_s8(sm[(m0 + mt * 16 + l15) * 9 + s * 4 + q4]);
#pragma unroll
      for (int nt = 0; nt < 4; ++nt)
        bfr[nt] = as_s8(sm[1152 + (n0 + nt * 16 + l15) * 9 + s * 4 + q4]);
#pragma unroll
      for (int mt = 0; mt < 4; ++mt)
#pragma unroll
        for (int nt = 0; nt < 4; ++nt)
          acc[mt][nt] = __builtin_amdgcn_mfma_f32_16x16x32_bf16(af[mt], bfr[nt], acc[mt][nt], 0, 0, 0);
    }
  }
  float nkv[4], lkv[4];
#pragma unroll
  for (int nt = 0; nt < 4; ++nt) {
    int gc = bn * 128 + n0 + nt * 16 + l15;
    nkv[nt] = nk[gc]; lkv[nt] = lk[gc];
  }
#pragma unroll
  for (int mt = 0; mt < 4; ++mt)
#pragma unroll
    for (int reg = 0; reg < 4; ++reg) {
      int gr = bm * 128 + m0 + mt * 16 + q4 * 4 + reg;
      float nqv = nq[gr], lqv = lq[gr];
#pragma unroll
      for (int nt = 0; nt < 4; ++nt) {
        int gc = bn * 128 + n0 + nt * 16 + l15;
        float d2 = nqv + nkv[nt] - 2.f * acc[mt][nt][reg];
        float Dv = sqrtf(fmaxf(d2, 0.f));
        Dout[gr * 2048 + gc] = Dv;
        float Pv = fabsf(lqv - lkv[nt]);
        DPo[gr * 2048 + gc] = pack_bf16x2(Dv, Pv);
      }
    }
}

// ---------------- fused conv, R7 structure + 46-row tile (R10 verified best) ----------------
// R12: exact revert to R10 (444.2 µs total, fused 353.8, VGPR 120, zero
// spills). R11's static-phase rings spilled (WRITE_SIZE 18->86 MB): the 5-case
// switch keeps all 10 ring slots live across case boundaries — the mov-shifting
// ring is the cheaper encoding at this register occupancy. Structural probes
// now adjudicated: barrier drain (R1 -2.5%), 2-row intervals (R2 0), straight-
// line (R6 +15% at 2w/SIMD), LDS lookahead (R7 +1.4%), MFMA balance (R8 -6.6%),
// makespan h=46 (R9/R10 +13%), ring de-mov (R11 spills). Issue port saturated:
// MFMA 41.7% + VALU 34% + DS ~25% at 2 waves/SIMD; registers pinned both ways.
__global__ __launch_bounds__(512, 2) void fused_conv(
    const unsigned* __restrict__ DPg, const float* __restrict__ Dmat,
    const unsigned short* __restrict__ W1g, const unsigned short* __restrict__ W2g,
    const unsigned short* __restrict__ W3g,
    const float* __restrict__ b1, const float* __restrict__ b2, const float* __restrict__ b3,
    float* __restrict__ Sout) {
  __shared__ int4 a1s[1600];       // [5][80][4]  slot 4 = scratch
  __shared__ int4 a2s[1360];       // [5][68][4]  slot 4 = scratch
  __shared__ unsigned dps[1700];   // [17][100]   row 16 = scratch
  const int t = threadIdx.x;
  const int wv = t >> 6, l = t & 63, l15 = l & 15, q4 = l >> 4;
  const int x0 = blockIdx.x * 62, y0 = blockIdx.y * 46;

  int4 uni[25];     // conv2: W2[dy][s] ; conv3: shift regs [tt][3]
  int4 uni2[5];     // conv2: acc ring tile0 ; conv1: W1p[j] ; conv3: W3[dx]
  int4 ring2[5];    // conv2 only: acc ring tile1
  float bias4[4];
  const int cls = (wv < 4) ? 0 : (wv < 6 ? 1 : 2);
  const int mb = (cls == 0) ? (wv >> 1) : (wv & 1);
  const int tp = (wv & 1) * 2;          // conv2 tile-pair base (tiles tp, tp+1)
  const int T3 = (wv - 6) * 2;

  // staging pipeline registers (cls 2 only) — two rows in flight
  unsigned pvO0 = 0u, pvO1 = 0u;
  float d0Oa = 0.f, d1Oa = 0.f, d0Ob = 0.f, d1Ob = 0.f;
  const int spx = (wv == 6) ? l : (64 + l);
  const int sgx = x0 - 5 + spx;
  const bool scol = (spx < 96) && (sgx >= 0) && (sgx < 2048);
  const int sgxc = min(max(sgx, 0), 2047);

  if (cls == 0) {
    const int4* W2i = (const int4*)W2g;
#pragma unroll
    for (int d = 0; d < 5; ++d)
#pragma unroll
      for (int s = 0; s < 5; ++s)
        uni[d * 5 + s] = W2i[(d * 32 + mb * 16 + l15) * 20 + s * 4 + q4];
#pragma unroll
    for (int j = 0; j < 5; ++j) { uni2[j] = make_int4(0, 0, 0, 0); ring2[j] = make_int4(0, 0, 0, 0); }
#pragma unroll
    for (int i = 0; i < 4; ++i) {
      int ch = mb * 16 + q4 * 4 + i;
      bias4[i] = (ch < 30) ? b2[ch] : 0.f;
    }
  } else if (cls == 1) {
    const int4* W1i = (const int4*)W1g;
#pragma unroll
    for (int j = 0; j < 3; ++j) uni2[j] = W1i[(j * 32 + mb * 16 + l15) * 4 + q4];
#pragma unroll
    for (int i = 0; i < 4; ++i) {
      int ch = mb * 16 + q4 * 4 + i;
      bias4[i] = (ch < 30) ? b1[ch] : 0.f;
    }
  } else {
    const int4* W3i = (const int4*)W3g;
#pragma unroll
    for (int dx = 0; dx < 3; ++dx)
      uni2[dx] = (l15 < 3) ? W3i[(l15 * 3 + dx) * 4 + q4] : make_int4(0, 0, 0, 0);
#pragma unroll
    for (int j = 0; j < 6; ++j) uni[j] = make_int4(0, 0, 0, 0);
    bias4[0] = b3[0];
    // prologue: preload DP rows y0+1, y0+2 (written to ring at end of first interval)
    if (scol) {
      pvO0 = DPg[(y0 + 1) * 2048 + sgx];
      pvO1 = DPg[(y0 + 2) * 2048 + sgx];
    }
  }
  // prefill DP rows y0-5 .. y0 (576 items over 512 threads: two passes)
  {
    int row = y0 - 5 + t / 96, px = t % 96;
    int gx = x0 - 5 + px;
    unsigned v = 0u;
    if (row >= 0 && row < 2048 && gx >= 0 && gx < 2048) v = DPg[row * 2048 + gx];
    dps[(row & 15) * 100 + px] = v;
  }
  {
    int t2 = t + 512;
    if (t2 < 576) {
      int row = y0 - 5 + t2 / 96, px = t2 % 96;
      int gx = x0 - 5 + px;
      unsigned v = 0u;
      if (row >= 0 && row < 2048 && gx >= 0 && gx < 2048) v = DPg[row * 2048 + gx];
      dps[(row & 15) * 100 + px] = v;
    }
  }
  // zero act2 pad px 64..67 (all 5 slots: 80 int4)
  if (t >= 144 && t < 224) {
    int i = t - 144;
    int sl = i / 16, rem = i & 15;
    a2s[(sl * 68 + 64 + (rem >> 2)) * 4 + (rem & 3)] = make_int4(0, 0, 0, 0);
  }
  __syncthreads();

  for (int r = y0 - 3; r <= y0 + 51; r += 2) {
    if (cls == 0) {
      // ---- conv2: two substeps (act1 rows r-2, r-1), two tiles, s+1 lookahead ----
#pragma unroll
      for (int sub = 0; sub < 2; ++sub) {
        int rc = r - 2 + sub;
        int s4 = rc & 3;
        // prime s=0 fragments
        int px0A = tp * 16 + l15;
        int px0B = px0A + 16;
        s8v fa = as_s8(a1s[(s4 * 80 + px0A) * 4 + (q4 ^ ((px0A >> 1) & 3))]);
        s8v fb = as_s8(a1s[(s4 * 80 + px0B) * 4 + (q4 ^ ((px0B >> 1) & 3))]);
        __builtin_amdgcn_s_setprio(1);
#pragma unroll
        for (int s = 0; s < 5; ++s) {
          s8v na = fa, nb = fb;
          if (s < 4) {     // issue next-tap reads BEFORE this tap's MFMA cluster
            int pxA = tp * 16 + l15 + s + 1;
            int pxB = pxA + 16;
            na = as_s8(a1s[(s4 * 80 + pxA) * 4 + (q4 ^ ((pxA >> 1) & 3))]);
            nb = as_s8(a1s[(s4 * 80 + pxB) * 4 + (q4 ^ ((pxB >> 1) & 3))]);
          }
#pragma unroll
          for (int d = 4; d >= 0; --d)
            uni2[4 - d] = as_i4(__builtin_amdgcn_mfma_f32_16x16x32_bf16(
                as_s8(uni[d * 5 + s]), fa, as_f4(uni2[4 - d]), 0, 0, 0));
#pragma unroll
          for (int d = 4; d >= 0; --d)
            ring2[4 - d] = as_i4(__builtin_amdgcn_mfma_f32_16x16x32_bf16(
                as_s8(uni[d * 5 + s]), fb, as_f4(ring2[4 - d]), 0, 0, 0));
          fa = na; fb = nb;
        }
        __builtin_amdgcn_s_setprio(0);
        // emit act2 row rc-2 for both tiles (branchless; scratch slot 4 if oob)
        int r2c = rc - 2;
        bool vrow = (r2c >= y0 - 1 && r2c <= y0 + 46);
        int slotrow = vrow ? (r2c & 3) : 4;
        bool rowin = vrow && (r2c >= 0) && (r2c < 2048);
        {
          int px2 = tp * 16 + l15;
          int gx2 = x0 - 1 + px2;
          bool ok = rowin && (gx2 >= 0) && (gx2 < 2048);
          f4v a = as_f4(uni2[0]);
          float v0 = ok ? fmaxf(a[0] + bias4[0], 0.f) : 0.f;
          float v1 = ok ? fmaxf(a[1] + bias4[1], 0.f) : 0.f;
          float v2 = ok ? fmaxf(a[2] + bias4[2], 0.f) : 0.f;
          float v3 = ok ? fmaxf(a[3] + bias4[3], 0.f) : 0.f;
          int slot = (mb * 2 + (q4 >> 1)) ^ ((px2 >> 1) & 3);
          *(uint2*)((unsigned short*)a2s + (slotrow * 68 + px2) * 32 + slot * 8 + (q4 & 1) * 4) =
              make_uint2(pack_bf16x2(v0, v1), pack_bf16x2(v2, v3));
        }
        {
          int px2 = tp * 16 + 16 + l15;
          int gx2 = x0 - 1 + px2;
          bool ok = rowin && (gx2 >= 0) && (gx2 < 2048);
          f4v a = as_f4(ring2[0]);
          float v0 = ok ? fmaxf(a[0] + bias4[0], 0.f) : 0.f;
          float v1 = ok ? fmaxf(a[1] + bias4[1], 0.f) : 0.f;
          float v2 = ok ? fmaxf(a[2] + bias4[2], 0.f) : 0.f;
          float v3 = ok ? fmaxf(a[3] + bias4[3], 0.f) : 0.f;
          int slot = (mb * 2 + (q4 >> 1)) ^ ((px2 >> 1) & 3);
          *(uint2*)((unsigned short*)a2s + (slotrow * 68 + px2) * 32 + slot * 8 + (q4 & 1) * 4) =
              make_uint2(pack_bf16x2(v0, v1), pack_bf16x2(v2, v3));
        }
        // shift both rings
#pragma unroll
        for (int j = 0; j < 4; ++j) { uni2[j] = uni2[j + 1]; ring2[j] = ring2[j + 1]; }
        uni2[4] = make_int4(0, 0, 0, 0);
        ring2[4] = make_int4(0, 0, 0, 0);
      }
    } else if (cls == 1) {
      // ---- conv1: produce act1 rows r and r+1, T1+1 lookahead ----
#pragma unroll
      for (int pr = 0; pr < 2; ++pr) {
        int p = r + pr;
        f4v a5[5];
        // prime T1=0 reads
        int4 c0, c1, c2;
        {
          int px = l15;
          int rl0 = p - 2, rl1 = p, rl2 = p + 2;
          int rs0 = (q4 < 2) ? rl0 : (rl0 + 1);
          int rs1 = (q4 < 2) ? rl1 : (rl1 + 1);
          c0 = *(const int4*)(dps + (rs0 & 15) * 100 + px + (q4 & 1) * 4);
          c1 = *(const int4*)(dps + (rs1 & 15) * 100 + px + (q4 & 1) * 4);
          c2 = *(const int4*)(dps + (rl2 & 15) * 100 + px + (q4 & 1) * 4);
        }
        __builtin_amdgcn_s_setprio(1);
#pragma unroll
        for (int T1 = 0; T1 < 5; ++T1) {
          int4 n0 = c0, n1 = c1, n2 = c2;
          if (T1 < 4) {  // issue next-tile reads BEFORE this tile's MFMAs
            int px = (T1 + 1) * 16 + l15;
            int rl0 = p - 2, rl1 = p, rl2 = p + 2;
            int rs0 = (q4 < 2) ? rl0 : (rl0 + 1);
            int rs1 = (q4 < 2) ? rl1 : (rl1 + 1);
            n0 = *(const int4*)(dps + (rs0 & 15) * 100 + px + (q4 & 1) * 4);
            n1 = *(const int4*)(dps + (rs1 & 15) * 100 + px + (q4 & 1) * 4);
            n2 = *(const int4*)(dps + (rl2 & 15) * 100 + px + (q4 & 1) * 4);
          }
          f4v acc = {0.f, 0.f, 0.f, 0.f};
          acc = __builtin_amdgcn_mfma_f32_16x16x32_bf16(as_s8(uni2[0]), as_s8(c0), acc, 0, 0, 0);
          acc = __builtin_amdgcn_mfma_f32_16x16x32_bf16(as_s8(uni2[1]), as_s8(c1), acc, 0, 0, 0);
          acc = __builtin_amdgcn_mfma_f32_16x16x32_bf16(as_s8(uni2[2]), as_s8(c2), acc, 0, 0, 0);
          a5[T1] = acc;
          c0 = n0; c1 = n1; c2 = n2;
        }
        __builtin_amdgcn_s_setprio(0);
        bool vrow = (p >= y0 - 3 && p <= y0 + 48);
        int slotrow = vrow ? (p & 3) : 4;
        bool rowok = vrow && (p >= 0 && p < 2048);
#pragma unroll
        for (int T1 = 0; T1 < 5; ++T1) {
          int px = T1 * 16 + l15;
          int gx = x0 - 3 + px;
          bool ok = rowok && gx >= 0 && gx < 2048;
          float v0 = ok ? fmaxf(a5[T1][0] + bias4[0], 0.f) : 0.f;
          float v1 = ok ? fmaxf(a5[T1][1] + bias4[1], 0.f) : 0.f;
          float v2 = ok ? fmaxf(a5[T1][2] + bias4[2], 0.f) : 0.f;
          float v3 = ok ? fmaxf(a5[T1][3] + bias4[3], 0.f) : 0.f;
          int slot = (mb * 2 + (q4 >> 1)) ^ ((px >> 1) & 3);
          *(uint2*)((unsigned short*)a1s + (slotrow * 80 + px) * 32 + slot * 8 + (q4 & 1) * 4) =
              make_uint2(pack_bf16x2(v0, v1), pack_bf16x2(v2, v3));
        }
      }
    } else {
      // ---- staging loads for DP rows r+6, r+7 (clamped, branchless) ----
      int rsN0 = r + 6, rsN1 = r + 7;
      unsigned tmp0 = DPg[min(rsN0, 2047) * 2048 + sgxc];
      unsigned tmp1 = DPg[min(rsN1, 2047) * 2048 + sgxc];
      unsigned pvN0 = (scol && rsN0 < 2048) ? tmp0 : 0u;
      unsigned pvN1 = (scol && rsN1 < 2048) ? tmp1 : 0u;
      // ---- residual loads for out rows r-5, r-4 (clamped, branchless) ----
      int gx0 = x0 + T3 * 16 + l15;
      int gx0c = min(gx0, 2047), gx1c = min(gx0 + 16, 2047);
      int yn0c = min(max(r - 5, 0), 2047), yn1c = min(max(r - 4, 0), 2047);
      float d0Na = Dmat[yn0c * 2048 + gx0c];
      float d1Na = Dmat[yn0c * 2048 + gx1c];
      float d0Nb = Dmat[yn1c * 2048 + gx0c];
      float d1Nb = Dmat[yn1c * 2048 + gx1c];
      // ---- hoist ALL conv3 LDS reads (both substeps) above the MFMA clusters ----
      s8v Bf[12];   // [sub*6 + tt*3 + dx]
#pragma unroll
      for (int sub = 0; sub < 2; ++sub) {
        int s4 = (r - 6 + sub) & 3;
#pragma unroll
        for (int tt = 0; tt < 2; ++tt)
#pragma unroll
          for (int dx = 0; dx < 3; ++dx) {
            int px2 = (T3 + tt) * 16 + l15 + dx;
            Bf[sub * 6 + tt * 3 + dx] =
                as_s8(a2s[(s4 * 68 + px2) * 4 + (q4 ^ ((px2 >> 1) & 3))]);
          }
      }
      // ---- conv3 substep A: consume act2 row r-6 (unconditional) ----
      float eA0, eA1, eA2, eA3, eA4, eA5;
      {
        __builtin_amdgcn_s_setprio(1);
#pragma unroll
        for (int tt = 0; tt < 2; ++tt) {
          f4v acc3 = {0.f, 0.f, 0.f, 0.f};
#pragma unroll
          for (int dx = 0; dx < 3; ++dx)
            acc3 = __builtin_amdgcn_mfma_f32_16x16x32_bf16(
                as_s8(uni2[dx]), Bf[tt * 3 + dx], acc3, 0, 0, 0);
          uni[tt * 3 + 2] = as_i4(acc3);
        }
        __builtin_amdgcn_s_setprio(0);
        eA0 = as_f4(uni[0])[0]; eA1 = as_f4(uni[1])[1]; eA2 = as_f4(uni[2])[2];
        eA3 = as_f4(uni[3])[0]; eA4 = as_f4(uni[4])[1]; eA5 = as_f4(uni[5])[2];
#pragma unroll
        for (int tt = 0; tt < 2; ++tt) {
          uni[tt * 3 + 0] = uni[tt * 3 + 1];
          uni[tt * 3 + 1] = uni[tt * 3 + 2];
        }
      }
      // ---- conv3 substep B: consume act2 row r-5 (unconditional) ----
      float eB0, eB1, eB2, eB3, eB4, eB5;
      {
        __builtin_amdgcn_s_setprio(1);
#pragma unroll
        for (int tt = 0; tt < 2; ++tt) {
          f4v acc3 = {0.f, 0.f, 0.f, 0.f};
#pragma unroll
          for (int dx = 0; dx < 3; ++dx)
            acc3 = __builtin_amdgcn_mfma_f32_16x16x32_bf16(
                as_s8(uni2[dx]), Bf[6 + tt * 3 + dx], acc3, 0, 0, 0);
          uni[tt * 3 + 2] = as_i4(acc3);
        }
        __builtin_amdgcn_s_setprio(0);
        eB0 = as_f4(uni[0])[0]; eB1 = as_f4(uni[1])[1]; eB2 = as_f4(uni[2])[2];
        eB3 = as_f4(uni[3])[0]; eB4 = as_f4(uni[4])[1]; eB5 = as_f4(uni[5])[2];
#pragma unroll
        for (int tt = 0; tt < 2; ++tt) {
          uni[tt * 3 + 0] = uni[tt * 3 + 1];
          uni[tt * 3 + 1] = uni[tt * 3 + 2];
        }
      }
      // ---- deferred emits: out rows r-7 (A), r-6 (B) — exec-masked stores ----
      {
        int y = r - 7;
        bool yok = (y >= y0 && y <= y0 + 45 && y < 2048);
        int gxa = x0 + T3 * 16 + l15;
        int gxb = gxa + 16;
        if (q4 == 0 && yok && gxa < 2048)
          Sout[y * 2048 + gxa] = eA0 + eA1 + eA2 + bias4[0] + d0Oa;
        if (q4 == 0 && yok && (T3 + 1) * 16 + l15 < 62 && gxb < 2048)
          Sout[y * 2048 + gxb] = eA3 + eA4 + eA5 + bias4[0] + d1Oa;
      }
      {
        int y = r - 6;
        bool yok = (y >= y0 && y <= y0 + 45 && y < 2048);
        int gxa = x0 + T3 * 16 + l15;
        int gxb = gxa + 16;
        if (q4 == 0 && yok && gxa < 2048)
          Sout[y * 2048 + gxa] = eB0 + eB1 + eB2 + bias4[0] + d0Ob;
        if (q4 == 0 && yok && (T3 + 1) * 16 + l15 < 62 && gxb < 2048)
          Sout[y * 2048 + gxb] = eB3 + eB4 + eB5 + bias4[0] + d1Ob;
      }
      // ---- write staging rows r+4, r+5 (scratch-redirected) ----
      {
        int rs0 = r + 4, rs1 = r + 5;
        int wr0 = (rs0 <= y0 + 50) ? (rs0 & 15) : 16;
        int wr1 = (rs1 <= y0 + 50) ? (rs1 & 15) : 16;
        if (spx < 96) {
          dps[wr0 * 100 + spx] = pvO0;
          dps[wr1 * 100 + spx] = pvO1;
        }
      }
      pvO0 = pvN0; pvO1 = pvN1;
      d0Oa = d0Na; d1Oa = d1Na; d0Ob = d0Nb; d1Ob = d1Nb;
    }
    bar_lgkm();
  }
}

// ---------------- row softmax (in-place, float4-vectorized) + dis accumulation ----------------
__global__ __launch_bounds__(256) void softmax_kernel(
    float* __restrict__ S, const float* __restrict__ Dmat, float* __restrict__ accum) {
  const int row = blockIdx.x, t = threadIdx.x;
  float* Srow = S + row * 2048;
  const float* Drow = Dmat + row * 2048;
  float4 s0 = ((const float4*)Srow)[2 * t];
  float4 s1 = ((const float4*)Srow)[2 * t + 1];
  float4 g0 = ((const float4*)Drow)[2 * t];
  float4 g1 = ((const float4*)Drow)[2 * t + 1];
  float sv[8] = {-s0.x, -s0.y, -s0.z, -s0.w, -s1.x, -s1.y, -s1.z, -s1.w};
  float dv[8] = {g0.x, g0.y, g0.z, g0.w, g1.x, g1.y, g1.z, g1.w};
  float mx = -1e30f;
#pragma unroll
  for (int i = 0; i < 8; ++i) mx = fmaxf(mx, sv[i]);
  __shared__ float red[4], redz[4], redw[4];
  for (int off = 32; off; off >>= 1) mx = fmaxf(mx, __shfl_xor(mx, off));
  const int wv = t >> 6, l = t & 63;
  if (l == 0) red[wv] = mx;
  __syncthreads();
  mx = fmaxf(fmaxf(red[0], red[1]), fmaxf(red[2], red[3]));
  float z = 0.f, w = 0.f, ev[8];
#pragma unroll
  for (int i = 0; i < 8; ++i) {
    ev[i] = __expf(sv[i] - mx);
    z += ev[i];
    w += ev[i] * dv[i];
  }
  for (int off = 32; off; off >>= 1) { z += __shfl_xor(z, off); w += __shfl_xor(w, off); }
  if (l == 0) { redz[wv] = z; redw[wv] = w; }
  __syncthreads();
  z = redz[0] + redz[1] + redz[2] + redz[3];
  w = redw[0] + redw[1] + redw[2] + redw[3];
  float inv = 1.f / z;
  float4 o0 = make_float4(ev[0] * inv, ev[1] * inv, ev[2] * inv, ev[3] * inv);
  float4 o1 = make_float4(ev[4] * inv, ev[5] * inv, ev[6] * inv, ev[7] * inv);
  ((float4*)Srow)[2 * t] = o0;
  ((float4*)Srow)[2 * t + 1] = o1;
  if (t == 0) atomicAdd(accum, w * inv);
}

__global__ void finalize_kernel(const float* __restrict__ accum, float* __restrict__ out) {
  if (threadIdx.x == 0) out[0] = accum[0] * (1.f / 2048.f);
}

// ---------------- host ----------------
extern "C" void kernel_launch(void* const* d_in, const int* in_sizes, int n_in,
                              void* d_out, int out_size, void* d_ws, size_t ws_size,
                              hipStream_t stream) {
  const float* seq_q = (const float*)d_in[0];
  const float* seq_k = (const float*)d_in[1];
  const float* len_q = (const float*)d_in[2];
  const float* len_k = (const float*)d_in[3];
  const float* w1 = (const float*)d_in[4];
  const float* b1 = (const float*)d_in[5];
  const float* w2 = (const float*)d_in[6];
  const float* b2 = (const float*)d_in[7];
  const float* w3 = (const float*)d_in[8];
  const float* b3 = (const float*)d_in[9];

  char* ws = (char*)d_ws;
  unsigned short* Qb  = (unsigned short*)(ws);                         // 2 MiB
  unsigned short* Kb  = (unsigned short*)(ws + ((size_t)2 << 20));     // 2 MiB
  float* nq           = (float*)(ws + ((size_t)4 << 20));              // 8 KiB
  float* nk           = (float*)(ws + ((size_t)4 << 20) + 16384);
  unsigned short* W1  = (unsigned short*)(ws + ((size_t)4 << 20) + 32768);   // 6 KiB (packed)
  unsigned short* W2  = (unsigned short*)(ws + ((size_t)4 << 20) + 65536);   // 50 KiB
  unsigned short* W3  = (unsigned short*)(ws + ((size_t)4 << 20) + 131072);  // 576 B
  float* accum        = (float*)(ws + ((size_t)4 << 20) + 163840);
  float* Dmat         = (float*)(ws + ((size_t)5 << 20));              // 16 MiB fp32
  unsigned* DPo       = (unsigned*)(ws + ((size_t)22 << 20));          // 16 MiB packed (D,P)
  float* out = (float*)d_out;

  // prep: casts+norms fused (2*NQ4, block-aligned) + weights + accum
  const int prep_total = 2 * ((2048 * 512) / 4) + 3072 + 25600 + 288 + 1;
  prep_kernel<<<(prep_total + 255) / 256, 256, 0, stream>>>(
      seq_q, seq_k, w1, w2, w3, Qb, Kb, W1, W2, W3, nq, nk, accum);
  dgemm_kernel<<<dim3(16, 16), 256, 0, stream>>>(Qb, Kb, nq, nk, len_q, len_k, Dmat, DPo);
  fused_conv<<<dim3(34, 45), 512, 0, stream>>>(
      DPo, Dmat, W1, W2, W3, b1, b2, b3, out);
  softmax_kernel<<<2048, 256, 0, stream>>>(out, Dmat, accum);
  finalize_kernel<<<1, 64, 0, stream>>>(accum, out + 4194304);
}